// Round 10
// baseline (175.716 us; speedup 1.0000x reference)
//
#include <hip/hip_runtime.h>
#include <hip/hip_bf16.h>
#include <hip/hip_fp8.h>

#define NNODE 50000
#define MTOT  100000   // 2*NNODE rows
#define NF    256
#define KNB   10

typedef unsigned short u16;
typedef float f32x4 __attribute__((ext_vector_type(4)));
typedef float f32x2 __attribute__((ext_vector_type(2)));
typedef short bf16x8 __attribute__((ext_vector_type(8)));

__device__ __forceinline__ u16 f2bf(float f) {
    unsigned u = __builtin_bit_cast(unsigned, f);
    unsigned r = (u + 0x7fffu + ((u >> 16) & 1u)) >> 16;
    return (u16)r;
}
__device__ __forceinline__ unsigned char f2f8(float f) {
    return (unsigned char)__hip_fp8_e4m3(f).__x;
}
__device__ __forceinline__ float f8tof(unsigned char b) {
    __hip_fp8_e4m3 h;
    h.__x = (__hip_fp8_storage_t)b;
    return (float)h;
}
template <int WORD>
__device__ __forceinline__ f32x2 cvt2_fp8(unsigned v) {
#if __has_builtin(__builtin_amdgcn_cvt_pk_f32_fp8)
    auto c = __builtin_amdgcn_cvt_pk_f32_fp8((int)v, WORD);
    f32x2 r; r.x = c[0]; r.y = c[1];
    return r;
#else
    unsigned s = WORD ? (v >> 16) : v;
    f32x2 r;
    r.x = f8tof((unsigned char)(s & 0xff));
    r.y = f8tof((unsigned char)((s >> 8) & 0xff));
    return r;
#endif
}
template <int WORD>
__device__ __forceinline__ unsigned pk_fp8(float a, float b, unsigned old) {
#if __has_builtin(__builtin_amdgcn_cvt_pk_fp8_f32)
    return (unsigned)__builtin_amdgcn_cvt_pk_fp8_f32(a, b, (int)old, WORD);
#else
    unsigned lo = (unsigned)f2f8(a) | ((unsigned)f2f8(b) << 8);
    return WORD ? ((old & 0x0000ffffu) | (lo << 16)) : ((old & 0xffff0000u) | lo);
#endif
}

// ---- kernel 1: merged cast.
//  [0,12500): Z -> bf16 Zleft + fp8 Z8
//  [12500,12756): WT bf16 [256 n][256 k] = Wr^T
//  [12756,13012): WT8 fp8 [256 n][256 k] = Wnr^T (plain layout)
__global__ __launch_bounds__(256) void cast_all(const float* __restrict__ Z1,
                                                const float* __restrict__ Z2,
                                                const float* __restrict__ Wr,
                                                const float* __restrict__ Wnr,
                                                u16* __restrict__ Zleft,
                                                unsigned char* __restrict__ Z8,
                                                u16* __restrict__ WT,
                                                unsigned char* __restrict__ WT8) {
    int b = blockIdx.x;
    if (b < 12500) {
        unsigned id = b * 256 + threadIdx.x;
        int m = id >> 5;
        int d = (id & 31) << 3;
        const float* src = (m < NNODE) ? (Z1 + (size_t)m * 256 + d)
                                       : (Z2 + (size_t)(m - NNODE) * 256 + d);
        float4 a = *(const float4*)src;
        float4 bb = *(const float4*)(src + 4);
        uint4 o;
        o.x = (unsigned)f2bf(a.x) | ((unsigned)f2bf(a.y) << 16);
        o.y = (unsigned)f2bf(a.z) | ((unsigned)f2bf(a.w) << 16);
        o.z = (unsigned)f2bf(bb.x) | ((unsigned)f2bf(bb.y) << 16);
        o.w = (unsigned)f2bf(bb.z) | ((unsigned)f2bf(bb.w) << 16);
        *(uint4*)(Zleft + (size_t)m * 256 + d) = o;
        uint2 o8;
        o8.x = (unsigned)f2f8(a.x) | ((unsigned)f2f8(a.y) << 8) |
               ((unsigned)f2f8(a.z) << 16) | ((unsigned)f2f8(a.w) << 24);
        o8.y = (unsigned)f2f8(bb.x) | ((unsigned)f2f8(bb.y) << 8) |
               ((unsigned)f2f8(bb.z) << 16) | ((unsigned)f2f8(bb.w) << 24);
        *(uint2*)(Z8 + (size_t)m * 256 + d) = o8;
    } else if (b < 12756) {
        int id = (b - 12500) * 256 + threadIdx.x;
        int n = id >> 8, k = id & 255;
        WT[n * 256 + k] = f2bf(Wr[(size_t)k * 256 + n]);
    } else {
        int id = (b - 12756) * 256 + threadIdx.x;
        int n = id >> 8, k = id & 255;
        WT8[n * 256 + k] = f2f8(Wnr[(size_t)k * 256 + n]);
    }
}

// ---- consume gather packet of step s: average -> fp8 -> swizzled sZ write
__device__ __forceinline__ void consume(const uint2 (&gv)[KNB], unsigned mask, int cnt,
                                        int w, int lane, int s, unsigned char* sZ) {
    f32x2 a0 = {0.f, 0.f}, a1 = {0.f, 0.f}, a2 = {0.f, 0.f}, a3 = {0.f, 0.f};
    #pragma unroll
    for (int k = 0; k < KNB; ++k) {
        float mm = (float)((mask >> k) & 1u);
        f32x2 m2 = {mm, mm};
        a0 += m2 * cvt2_fp8<0>(gv[k].x);
        a1 += m2 * cvt2_fp8<1>(gv[k].x);
        a2 += m2 * cvt2_fp8<0>(gv[k].y);
        a3 += m2 * cvt2_fp8<1>(gv[k].y);
    }
    float sc = 1.0f / (float)(cnt > 0 ? cnt : 1);
    unsigned w0 = pk_fp8<0>(a0.x * sc, a0.y * sc, 0u);
    w0 = pk_fp8<1>(a1.x * sc, a1.y * sc, w0);
    unsigned w1 = pk_fp8<0>(a2.x * sc, a2.y * sc, 0u);
    w1 = pk_fp8<1>(a3.x * sc, a3.y * sc, w1);
    int rl = w * 8 + s * 2 + (lane >> 5);           // local row 0..31
    int gp = (lane & 31) ^ (rl & 7);
    *(uint2*)(sZ + rl * 256 + (gp << 3)) = make_uint2(w0, w1);
}

// ---- kernel 2: FUSED gather + GEMM, barrier-free halves.
// BM=32, BN=256. 256 thr = 4 waves (1M x 4N), wave tile 32x64 -> acc[2][4].
// A and B fragments are per-wave-private -> loaded global->VGPR directly (no LDS,
// no barriers). Only sZ (8KB gathered Zavg, fp8) uses LDS; ONE __syncthreads().
__global__ __launch_bounds__(256, 3) void gemm_fused(const u16* __restrict__ Zl,           // [MTOT][256] bf16
                                                     const unsigned char* __restrict__ Z8, // [MTOT][256] fp8
                                                     const u16* __restrict__ WT,           // [256][256] bf16 Wr^T
                                                     const unsigned char* __restrict__ WT8,// [256][256] fp8 Wnr^T
                                                     const int* __restrict__ n1,
                                                     const int* __restrict__ n2,
                                                     float* __restrict__ C) {
    __shared__ unsigned char sZ[32 * 256];   // 8 KB, 8B-granule XOR-swizzled
    // reversed block order: cast_all wrote high rows last -> first gemm blocks hit L3
    const int m0 = (3124 - blockIdx.x) * 32;
    const int t = threadIdx.x;
    const int lane = t & 63;
    const int w = t >> 6;           // wave 0..3 -> out-col group w*64
    const int hi = lane >> 4;
    const int l15 = lane & 15;

    f32x4 acc[2][4] = {};
    uint2 gv[KNB];
    int2 icur[5], inxt[5];
    unsigned pmask = 0;
    int pcnt = 0;

    // prologue: idx(0) for this lane's gather row
    {
        int g = m0 + w * 8 + (lane >> 5);
        int p = (g >= NNODE);
        const int* nb = (p ? n2 : n1) + (size_t)(g - p * NNODE) * KNB;
        #pragma unroll
        for (int q = 0; q < 5; ++q) icur[q] = *(const int2*)(nb + 2 * q);
    }

    // ---- left half: 4 steps of K=64, bf16, zero barriers
#define LSTEP(S)                                                              \
    do {                                                                      \
        const int kt = (S) * 64;                                              \
        bf16x8 af[2][2], bfr[2][4];                                           \
        _Pragma("unroll")                                                     \
        for (int k2 = 0; k2 < 2; ++k2) {                                      \
            int kq = kt + k2 * 32 + hi * 8;                                   \
            _Pragma("unroll")                                                 \
            for (int i = 0; i < 2; ++i)                                       \
                af[k2][i] = *(const bf16x8*)(Zl + (size_t)(m0 + i * 16 + l15) * 256 + kq); \
            _Pragma("unroll")                                                 \
            for (int j = 0; j < 4; ++j)                                       \
                bfr[k2][j] = *(const bf16x8*)(WT + (size_t)(w * 64 + j * 16 + l15) * 256 + kq); \
        }                                                                     \
        if ((S) < 3) {  /* idx(S+1) */                                        \
            int g = m0 + w * 8 + ((S) + 1) * 2 + (lane >> 5);                 \
            int p = (g >= NNODE);                                             \
            const int* nb = (p ? n2 : n1) + (size_t)(g - p * NNODE) * KNB;    \
            _Pragma("unroll")                                                 \
            for (int q = 0; q < 5; ++q) inxt[q] = *(const int2*)(nb + 2 * q); \
        }                                                                     \
        if ((S) > 0) consume(gv, pmask, pcnt, w, lane, (S) - 1, sZ);          \
        {   /* issue G(S) */                                                  \
            int g = m0 + w * 8 + (S) * 2 + (lane >> 5);                       \
            int p = (g >= NNODE);                                             \
            const unsigned char* zb = Z8 + (size_t)p * ((size_t)NNODE * 256) + ((lane & 31) << 3); \
            unsigned mask = 0;                                                \
            int cnt = 0;                                                      \
            _Pragma("unroll")                                                 \
            for (int k = 0; k < KNB; ++k) {                                   \
                int ix = (k & 1) ? icur[k >> 1].y : icur[k >> 1].x;           \
                int valid = (ix > -1) ? 1 : 0;                                \
                mask |= (unsigned)valid << k;                                 \
                cnt += valid;                                                 \
                gv[k] = *(const uint2*)(zb + (size_t)(valid ? ix : 0) * 256); \
            }                                                                 \
            pmask = mask;                                                     \
            pcnt = cnt;                                                       \
        }                                                                     \
        if ((S) < 3) {                                                        \
            _Pragma("unroll")                                                 \
            for (int q = 0; q < 5; ++q) icur[q] = inxt[q];                    \
        }                                                                     \
        _Pragma("unroll")                                                     \
        for (int k2 = 0; k2 < 2; ++k2)                                        \
            _Pragma("unroll")                                                 \
            for (int i = 0; i < 2; ++i)                                       \
                _Pragma("unroll")                                             \
                for (int j = 0; j < 4; ++j)                                   \
                    acc[i][j] = __builtin_amdgcn_mfma_f32_16x16x32_bf16(af[k2][i], bfr[k2][j], acc[i][j], 0, 0, 0); \
    } while (0)

    LSTEP(0);
    LSTEP(1);
    LSTEP(2);
    LSTEP(3);
#undef LSTEP

    // final consume + ONE barrier (sZ handoff)
    consume(gv, pmask, pcnt, w, lane, 3, sZ);
    __syncthreads();

    // ---- right half: 4 steps of K=64, fp8 x fp8, zero barriers
#define RSTEP(R)                                                              \
    do {                                                                      \
        _Pragma("unroll")                                                     \
        for (int m = 0; m < 2; ++m) {                                         \
            long long az[2], bz[4];                                           \
            _Pragma("unroll")                                                 \
            for (int i = 0; i < 2; ++i) {                                     \
                int row = i * 16 + l15;                                       \
                int g8 = (R) * 8 + m * 4 + hi;                                \
                az[i] = *(const long long*)(sZ + row * 256 + ((g8 ^ (row & 7)) << 3)); \
            }                                                                 \
            _Pragma("unroll")                                                 \
            for (int j = 0; j < 4; ++j) {                                     \
                int col = w * 64 + j * 16 + l15;                              \
                bz[j] = *(const long long*)(WT8 + (size_t)col * 256 + (R) * 64 + m * 32 + hi * 8); \
            }                                                                 \
            _Pragma("unroll")                                                 \
            for (int i = 0; i < 2; ++i)                                       \
                _Pragma("unroll")                                             \
                for (int j = 0; j < 4; ++j)                                   \
                    acc[i][j] = __builtin_amdgcn_mfma_f32_16x16x32_fp8_fp8(az[i], bz[j], acc[i][j], 0, 0, 0); \
        }                                                                     \
    } while (0)

    RSTEP(0);
    RSTEP(1);
    RSTEP(2);
    RSTEP(3);
#undef RSTEP

    // ---- epilogue: relu + store (C/D layout: col = lane&15, row = (lane>>4)*4 + q)
    #pragma unroll
    for (int i = 0; i < 2; ++i) {
        int rbase = m0 + i * 16 + (hi << 2);
        #pragma unroll
        for (int j = 0; j < 4; ++j) {
            int col = w * 64 + j * 16 + l15;
            #pragma unroll
            for (int q = 0; q < 4; ++q)
                C[(size_t)(rbase + q) * NF + col] = fmaxf(acc[i][j][q], 0.f);
        }
    }
}

extern "C" void kernel_launch(void* const* d_in, const int* in_sizes, int n_in,
                              void* d_out, int out_size, void* d_ws, size_t ws_size,
                              hipStream_t stream) {
    const float* Z1  = (const float*)d_in[0];
    const float* Z2  = (const float*)d_in[1];
    const float* Wr  = (const float*)d_in[2];
    const float* Wnr = (const float*)d_in[3];
    const int*   n1  = (const int*)d_in[4];
    const int*   n2  = (const int*)d_in[5];
    float* out = (float*)d_out;

    u16* WT            = (u16*)d_ws;                              // 128 KB
    unsigned char* WT8 = (unsigned char*)d_ws + 131072;           // 64 KB
    u16* Zleft         = (u16*)((unsigned char*)d_ws + 196608);   // 51.2 MB
    unsigned char* Z8  = (unsigned char*)d_ws + 196608 + (size_t)MTOT * 512;  // 25.6 MB

    cast_all<<<13012, 256, 0, stream>>>(Z1, Z2, Wr, Wnr, Zleft, Z8, WT, WT8);
    gemm_fused<<<3125, 256, 0, stream>>>(Zleft, Z8, WT, WT8, n1, n2, out);
}